// Round 5
// baseline (2319.740 us; speedup 1.0000x reference)
//
#include <hip/hip_runtime.h>
#include <math.h>

#define KTOK  32
#define DM    64
#define DH    16
#define NH    4
#define DFF   128
#define KVSTR 36   // 16 k + 16 v + 4 pad floats; 144B rows -> 16B-aligned float4 reads

__global__ __launch_bounds__(64, 2)
void ff_kernel(
    const int*   __restrict__ qidx,
    const int*   __restrict__ offs,
    const float* __restrict__ vals,
    const float* __restrict__ gscale,
    const int*   __restrict__ NxP,
    const int*   __restrict__ NyP,
    const int*   __restrict__ NtP,
    const float* __restrict__ lgam,
    const float* __restrict__ Wp,   const float* __restrict__ bp,
    const float* __restrict__ Wqkv, const float* __restrict__ bqkv,
    const float* __restrict__ Wo,   const float* __restrict__ bo,
    const float* __restrict__ W1w,  const float* __restrict__ b1w,
    const float* __restrict__ W2w,  const float* __restrict__ b2w,
    const float* __restrict__ ln1g, const float* __restrict__ ln1b,
    const float* __restrict__ ln2g, const float* __restrict__ ln2b,
    const float* __restrict__ hg,   const float* __restrict__ hb,
    const float* __restrict__ hW1,  const float* __restrict__ hb1,
    const float* __restrict__ hW2,  const float* __restrict__ hb2,
    float* __restrict__ out)
{
    __shared__ float kv[2][KTOK][KVSTR];   // 9216 B: this head's k[0:16] / v[16:32] per token

    const int tid = threadIdx.x;
    const int bl  = tid >> 5;        // which of the 2 queries in this block
    const int kk  = tid & 31;        // token index this lane owns
    const int b   = blockIdx.x * 2 + bl;

    const int Nx = NxP[0], Ny = NyP[0], Nt = NtP[0];
    const int NyNt = Ny * Nt;

    // ---- decode query cell ----
    const int q  = qidx[b];
    const int i0 = q / NyNt;
    const int r0 = q - i0 * NyNt;
    const int j0 = r0 / Nt;
    const int t0 = r0 - j0 * Nt;

    const int di = offs[kk*3+0], dj = offs[kk*3+1], dk = offs[kk*3+2];
    int I = i0 + di; if (I >= Nx) I -= Nx;     // di in [0,5), Nx >> 5
    int J = j0 + dj; if (J >= Ny) J -= Ny;
    int Kc = t0 + dk; if (Kc >= Nt) Kc -= Nt;
    const float val = vals[I*NyNt + J*Nt + Kc];

    const float r1 = (float)di * gscale[0] * expf(lgam[0]);
    const float r2 = (float)dj * gscale[1] * expf(lgam[1]);
    const float r3 = (float)dk * gscale[2] * expf(lgam[2]);

    // ---- input projection: h = tok @ Wp^T + bp ----
    float h[DM];
#pragma unroll
    for (int d = 0; d < DM; ++d)
        h[d] = bp[d] + Wp[d*4+0]*r1 + Wp[d*4+1]*r2 + Wp[d*4+2]*r3 + Wp[d*4+3]*val;

    // ================= transformer layers =================
    for (int l = 0; l < 2; ++l) {
        const float* Wq  = Wqkv + l*(3*DM)*DM;
        const float* bq  = bqkv + l*(3*DM);
        const float* WoL = Wo   + l*DM*DM;

        // attention output accumulator: x = h + bo + o@Wo^T (built per head)
        float xacc[DM];
#pragma unroll
        for (int dp = 0; dp < DM; ++dp) xacc[dp] = h[dp] + bo[l*DM+dp];

        for (int hh = 0; hh < NH; ++hh) {
            __syncthreads();   // previous head's LDS reads complete

            // ---- this head's k,v rows -> LDS (rolled t; direct LDS writes) ----
            for (int t = 0; t < DH; ++t) {
                const float* wk = Wq + (DM   + hh*DH + t)*DM;
                const float* wv = Wq + (2*DM + hh*DH + t)*DM;
                float ak0 = bq[DM+hh*DH+t],   ak1 = 0.f;
                float av0 = bq[2*DM+hh*DH+t], av1 = 0.f;
#pragma unroll
                for (int d = 0; d < DM; d += 2) {
                    ak0 = fmaf(h[d],   wk[d],   ak0);
                    ak1 = fmaf(h[d+1], wk[d+1], ak1);
                    av0 = fmaf(h[d],   wv[d],   av0);
                    av1 = fmaf(h[d+1], wv[d+1], av1);
                }
                kv[bl][kk][t]    = ak0 + ak1;
                kv[bl][kk][DH+t] = av0 + av1;
            }
            __syncthreads();

            // ---- q projection (unrolled: qh indices must be static) ----
            float qh[DH];
#pragma unroll
            for (int t = 0; t < DH; ++t) {
                const float* wq = Wq + (hh*DH + t)*DM;
                float a0 = bq[hh*DH + t], a1 = 0.f;
#pragma unroll
                for (int d = 0; d < DM; d += 2) {
                    a0 = fmaf(h[d],   wq[d],   a0);
                    a1 = fmaf(h[d+1], wq[d+1], a1);
                }
                qh[t] = (a0 + a1) * 0.25f;   // fold 1/sqrt(Dh)=1/4
            }

            // ---- scores (k reads are wave-uniform broadcasts) ----
            float sc[KTOK];
            float mx = -1e30f;
#pragma unroll
            for (int kx = 0; kx < KTOK; ++kx) {
                const float4* kr = (const float4*)&kv[bl][kx][0];
                float s0 = 0.f, s1 = 0.f;
#pragma unroll
                for (int t4 = 0; t4 < 4; ++t4) {
                    float4 k4 = kr[t4];
                    s0 = fmaf(qh[t4*4+0], k4.x, s0);
                    s1 = fmaf(qh[t4*4+1], k4.y, s1);
                    s0 = fmaf(qh[t4*4+2], k4.z, s0);
                    s1 = fmaf(qh[t4*4+3], k4.w, s1);
                }
                sc[kx] = s0 + s1;
                mx = fmaxf(mx, sc[kx]);
            }
            float den = 0.f;
#pragma unroll
            for (int kx = 0; kx < KTOK; ++kx) {
                float e = expf(sc[kx] - mx);
                sc[kx] = e; den += e;
            }
            const float inv = 1.f / den;

            // ---- PV ----
            float oh[DH];
#pragma unroll
            for (int t = 0; t < DH; ++t) oh[t] = 0.f;
#pragma unroll
            for (int kx = 0; kx < KTOK; ++kx) {
                const float w = sc[kx] * inv;
                const float4* vr = (const float4*)&kv[bl][kx][DH];
#pragma unroll
                for (int t4 = 0; t4 < 4; ++t4) {
                    float4 v4 = vr[t4];
                    oh[t4*4+0] = fmaf(w, v4.x, oh[t4*4+0]);
                    oh[t4*4+1] = fmaf(w, v4.y, oh[t4*4+1]);
                    oh[t4*4+2] = fmaf(w, v4.z, oh[t4*4+2]);
                    oh[t4*4+3] = fmaf(w, v4.w, oh[t4*4+3]);
                }
            }

            // ---- fold this head's o into xacc (static dp, static t) ----
#pragma unroll
            for (int dp = 0; dp < DM; ++dp) {
                const float* w = WoL + dp*DM + hh*DH;
                float s0 = 0.f, s1 = 0.f;
#pragma unroll
                for (int t = 0; t < DH; t += 2) {
                    s0 = fmaf(oh[t],   w[t],   s0);
                    s1 = fmaf(oh[t+1], w[t+1], s1);
                }
                xacc[dp] += s0 + s1;
            }
        }

        // ---- LN1 ----
        {
            float mean = 0.f;
#pragma unroll
            for (int dp = 0; dp < DM; ++dp) mean += xacc[dp];
            mean *= (1.f/DM);
            float var = 0.f;
#pragma unroll
            for (int dp = 0; dp < DM; ++dp) { float dx = xacc[dp]-mean; var = fmaf(dx,dx,var); }
            var *= (1.f/DM);
            const float rs = rsqrtf(var + 1e-5f);
#pragma unroll
            for (int dp = 0; dp < DM; ++dp)
                h[dp] = (xacc[dp]-mean)*rs*ln1g[l*DM+dp] + ln1b[l*DM+dp];
        }

        // ---- FF: f in chunks of 8; W2 read as contiguous 32B row segments ----
        float a2[DM];
#pragma unroll
        for (int dp = 0; dp < DM; ++dp) a2[dp] = h[dp] + b2w[l*DM+dp];
        const float* W1L = W1w + l*DFF*DM;
        const float* W2L = W2w + l*DM*DFF;
        for (int f0 = 0; f0 < DFF; f0 += 8) {
            float a[8];
#pragma unroll
            for (int fc = 0; fc < 8; ++fc) {
                const float* w1 = W1L + (f0+fc)*DM;
                float s0 = b1w[l*DFF+f0+fc], s1 = 0.f;
#pragma unroll
                for (int d = 0; d < DM; d += 2) {
                    s0 = fmaf(h[d],   w1[d],   s0);
                    s1 = fmaf(h[d+1], w1[d+1], s1);
                }
                a[fc] = fmaxf(s0 + s1, 0.f);
            }
#pragma unroll
            for (int dp = 0; dp < DM; ++dp) {
                const float* w2 = W2L + dp*DFF + f0;
                float t0 = fmaf(a[0], w2[0], fmaf(a[1], w2[1], fmaf(a[2], w2[2], a[3]*w2[3])));
                float t1 = fmaf(a[4], w2[4], fmaf(a[5], w2[5], fmaf(a[6], w2[6], a[7]*w2[7])));
                a2[dp] += t0 + t1;
            }
        }

        // ---- LN2 ----
        {
            float mean = 0.f;
#pragma unroll
            for (int dp = 0; dp < DM; ++dp) mean += a2[dp];
            mean *= (1.f/DM);
            float var = 0.f;
#pragma unroll
            for (int dp = 0; dp < DM; ++dp) { float dx = a2[dp]-mean; var = fmaf(dx,dx,var); }
            var *= (1.f/DM);
            const float rs = rsqrtf(var + 1e-5f);
#pragma unroll
            for (int dp = 0; dp < DM; ++dp)
                h[dp] = (a2[dp]-mean)*rs*ln2g[l*DM+dp] + ln2b[l*DM+dp];
        }
    }

    // ================= head: mean over tokens via shuffle butterfly =================
    float hm[DM];
#pragma unroll
    for (int d = 0; d < DM; ++d) {
        float v = h[d];
        v += __shfl_xor(v, 1,  64);
        v += __shfl_xor(v, 2,  64);
        v += __shfl_xor(v, 4,  64);
        v += __shfl_xor(v, 8,  64);
        v += __shfl_xor(v, 16, 64);   // masks <32: halves stay independent
        hm[d] = v * (1.f/KTOK);
    }
    {
        float mean = 0.f;
#pragma unroll
        for (int d = 0; d < DM; ++d) mean += hm[d];
        mean *= (1.f/DM);
        float var = 0.f;
#pragma unroll
        for (int d = 0; d < DM; ++d) { float dx = hm[d]-mean; var = fmaf(dx,dx,var); }
        var *= (1.f/DM);
        const float rs = rsqrtf(var + 1e-5f);
#pragma unroll
        for (int d = 0; d < DM; ++d)
            hm[d] = (hm[d]-mean)*rs*hg[d] + hb[d];
    }

    // ---- distributed head MLP: this lane owns rows kk and kk+32 ----
    float acc = 0.f;
#pragma unroll
    for (int zz = 0; zz < 2; ++zz) {
        const int zi = kk + zz*32;
        const float4* w4 = (const float4*)(hW1 + zi*DM);
        float a0 = hb1[zi], a1 = 0.f;
#pragma unroll
        for (int d4 = 0; d4 < DM/4; ++d4) {
            float4 w = w4[d4];
            a0 = fmaf(hm[d4*4+0], w.x, a0);
            a1 = fmaf(hm[d4*4+1], w.y, a1);
            a0 = fmaf(hm[d4*4+2], w.z, a0);
            a1 = fmaf(hm[d4*4+3], w.w, a1);
        }
        const float a = a0 + a1;
        const float g = 0.5f * a * (1.f + erff(a * 0.70710678118654752f));
        acc = fmaf(g, hW2[zi], acc);
    }
    acc += __shfl_xor(acc, 1,  64);
    acc += __shfl_xor(acc, 2,  64);
    acc += __shfl_xor(acc, 4,  64);
    acc += __shfl_xor(acc, 8,  64);
    acc += __shfl_xor(acc, 16, 64);

    if (kk == 0) out[b] = acc + hb2[0];
}

extern "C" void kernel_launch(void* const* d_in, const int* in_sizes, int n_in,
                              void* d_out, int out_size, void* d_ws, size_t ws_size,
                              hipStream_t stream) {
    const int*   qidx   = (const int*)  d_in[0];
    const int*   offs   = (const int*)  d_in[1];
    const float* vals   = (const float*)d_in[2];
    // d_in[3] coords: unused by the reference
    const float* gscale = (const float*)d_in[4];
    const int*   NxP    = (const int*)  d_in[5];
    const int*   NyP    = (const int*)  d_in[6];
    const int*   NtP    = (const int*)  d_in[7];
    const float* lgam   = (const float*)d_in[8];
    const float* Wp     = (const float*)d_in[9];
    const float* bp     = (const float*)d_in[10];
    const float* Wqkv   = (const float*)d_in[11];
    const float* bqkv   = (const float*)d_in[12];
    const float* Wo     = (const float*)d_in[13];
    const float* bo     = (const float*)d_in[14];
    const float* W1w    = (const float*)d_in[15];
    const float* b1w    = (const float*)d_in[16];
    const float* W2w    = (const float*)d_in[17];
    const float* b2w    = (const float*)d_in[18];
    const float* ln1g   = (const float*)d_in[19];
    const float* ln1b   = (const float*)d_in[20];
    const float* ln2g   = (const float*)d_in[21];
    const float* ln2b   = (const float*)d_in[22];
    const float* hg     = (const float*)d_in[23];
    const float* hb     = (const float*)d_in[24];
    const float* hW1    = (const float*)d_in[25];
    const float* hb1    = (const float*)d_in[26];
    const float* hW2    = (const float*)d_in[27];
    const float* hb2    = (const float*)d_in[28];
    float* outp = (float*)d_out;

    const int B = in_sizes[0];
    dim3 grid(B / 2), block(64);
    hipLaunchKernelGGL(ff_kernel, grid, block, 0, stream,
        qidx, offs, vals, gscale, NxP, NyP, NtP, lgam,
        Wp, bp, Wqkv, bqkv, Wo, bo, W1w, b1w, W2w, b2w,
        ln1g, ln1b, ln2g, ln2b, hg, hb, hW1, hb1, hW2, hb2, outp);
}